// Round 3
// baseline (201.680 us; speedup 1.0000x reference)
//
#include <hip/hip_runtime.h>
#include <hip/hip_bf16.h>
#include <math.h>

// DotProductAttention: B=16, Q=2048, K=2048, D=128, fp32 in/out.
// Mask is along the QUERY axis: rows q >= valid_lens[b] -> uniform softmax ->
// row = mean(V). Fully-masked q-tiles skip flash (finalize writes sumV/K);
// masked rows inside partial tiles use sc=0 -> p=1 -> same uniform result.
//
// Round 3 structure:
//  - S^T trick: compute S^T = K.Q^T with a key&4 tile split so the S^T
//    C-layout registers ARE the PV A-fragment (no P LDS round-trip at all).
//  - K-split SEG=8; segments atomic-add unnormalized O (fp32) and l into
//    accumulators; finalize kernel divides. Exact single-pass math.
//  - q-tile swizzle for CU load balance; Q pre-converted to f16.
//
// ws: [0,128K) Lacc | [128K,+8K) sumV | [+16.8M) Oacc | Kh 8M | Vt 8M | Qh 8M
// (~42 MB; round-2 run proved ws >= 84 MB).

#define Bn 16
#define Qn 2048
#define Kn 2048
#define Dn 128
#define BQ 64
#define KT 32
#define SEG 8
#define SCALE 0.08838834764831845f  // 1/sqrt(128)

typedef _Float16 f16;
typedef _Float16 f16x4_t __attribute__((ext_vector_type(4)));
typedef _Float16 f16x8_t __attribute__((ext_vector_type(8)));
typedef float f32x4_t __attribute__((ext_vector_type(4)));

// ---------------- fused prep: Q,K->f16, V->Vt f16 (transposed), colsum(V) ----
// grid (64, 4, 16) block (32,8)

__global__ void __launch_bounds__(256) prep_kernel(
    const float* __restrict__ Qg, const float* __restrict__ Kg,
    const float* __restrict__ Vg, f16* __restrict__ Qh, f16* __restrict__ Kh,
    f16* __restrict__ Vt, float* __restrict__ sv) {
  __shared__ float t[32][33];
  __shared__ float ps[8][32];
  const int b = blockIdx.z, k0 = blockIdx.x * 32, d0 = blockIdx.y * 32;
  const int x = threadIdx.x, y = threadIdx.y;

  // Q and K conversion: this block converts 1024 consecutive floats of each
  {
    int lb = (b * 4 + blockIdx.y) * 64 + blockIdx.x;  // 0..4095
    size_t off = (size_t)lb * 1024 + (size_t)(y * 32 + x) * 4;
    float4 f = *(const float4*)(Kg + off);
    f16x4_t o;
    o[0] = (f16)f.x; o[1] = (f16)f.y; o[2] = (f16)f.z; o[3] = (f16)f.w;
    *(f16x4_t*)(Kh + off) = o;
    float4 q = *(const float4*)(Qg + off);
    f16x4_t oq;
    oq[0] = (f16)q.x; oq[1] = (f16)q.y; oq[2] = (f16)q.z; oq[3] = (f16)q.w;
    *(f16x4_t*)(Qh + off) = oq;
  }

  // V 32x32 tile load (coalesced)
  const float* src = Vg + ((size_t)b * Kn + k0) * Dn + d0;
#pragma unroll
  for (int i = 0; i < 4; i++) t[y + 8 * i][x] = src[(size_t)(y + 8 * i) * Dn + x];
  __syncthreads();

  // transposed f16 store
  f16* dst = Vt + ((size_t)b * Dn + d0) * Kn + k0;
#pragma unroll
  for (int i = 0; i < 4; i++) dst[(size_t)(y + 8 * i) * Kn + x] = (f16)t[x][y + 8 * i];

  // column sums (over k) for the masked fast path
  float s = 0.f;
#pragma unroll
  for (int i = 0; i < 4; i++) s += t[y + 8 * i][x];
  ps[y][x] = s;
  __syncthreads();
  if (y == 0) {
    float tot = 0.f;
#pragma unroll
    for (int j = 0; j < 8; j++) tot += ps[j][x];
    atomicAdd(&sv[b * Dn + d0 + x], tot);
  }
}

// valid_lens may be stored as int32 or int64. Sniff: odd words all zero -> 64.
__device__ __forceinline__ int load_vl(const int* __restrict__ vlp, int b) {
  bool is64 = true;
#pragma unroll
  for (int i = 1; i < 16; i += 2) is64 = is64 && (vlp[i] == 0);
  return is64 ? vlp[2 * b] : vlp[b];
}

// ---------------- flash attention, S^T form, atomic accumulate ----------------
// grid (32, 16, SEG) block 256

__global__ void __launch_bounds__(256) flash_kernel(
    const f16* __restrict__ Qh, const f16* __restrict__ Kh,
    const f16* __restrict__ Vt, const int* __restrict__ vlp,
    float* __restrict__ Oacc, float* __restrict__ Lacc) {
  const int b = blockIdx.y;
  const int seg = blockIdx.z;
  const int qt = (blockIdx.x * 17 + seg) & 31;  // swizzle: scatter active tiles
  const int q0 = qt * BQ;
  const int vl = load_vl(vlp, b);
  if (q0 >= vl) return;  // fully masked tile: finalize handles it

  __shared__ __align__(16) f16 Ks[KT][Dn + 8];  // 32 x 136
  __shared__ __align__(16) f16 Vs[Dn][KT + 8];  // 128 x 40

  const int tid = threadIdx.x;
  const int wave = tid >> 6, lane = tid & 63;
  const int g = lane >> 4, c = lane & 15;
  const int qrow = q0 + wave * 16 + c;          // this lane's q-row (S^T col)
  const float sc = (qrow >= vl) ? 0.f : SCALE;  // masked row: s=0 -> p=1

  // Q fragment = B-operand of S^T mfma = A-layout of Q: Qh[qrow][dblk*32+g*8+j]
  f16x8_t qf[4];
  {
    const f16* qp = Qh + ((size_t)b * Qn + qrow) * Dn + g * 8;
#pragma unroll
    for (int dblk = 0; dblk < 4; dblk++) qf[dblk] = *(const f16x8_t*)(qp + dblk * 32);
  }

  f32x4_t O[8];
#pragma unroll
  for (int i = 0; i < 8; i++) O[i] = (f32x4_t){0.f, 0.f, 0.f, 0.f};
  float l_lane = 0.f;

  const f16* KhB = Kh + (size_t)b * Kn * Dn;
  const f16* VtB = Vt + (size_t)b * Dn * Kn;
  // key->tile-row map: tile0 rows m -> key (m>>2)*8+(m&3) (key&4==0),
  // tile1 -> +4. Then S^T C-layout regs of lane (c,g) are keys g*8+r (t0)
  // and g*8+4+r (t1) for q-row c == the PV A-fragment. No transform needed.
  const int kr0 = (c >> 2) * 8 + (c & 3);

  const int kt0 = seg * (Kn / SEG);
  for (int kt = kt0; kt < kt0 + Kn / SEG; kt += KT) {
    __syncthreads();
#pragma unroll
    for (int i = 0; i < 2; i++) {
      int idx = tid + i * 256;
      int kk = idx >> 4, dd = (idx & 15) * 8;
      *(int4*)(&Ks[kk][dd]) = *(const int4*)(KhB + (size_t)(kt + kk) * Dn + dd);
    }
#pragma unroll
    for (int i = 0; i < 2; i++) {
      int idx = tid + i * 256;
      int dd = idx >> 2, kk = (idx & 3) * 8;
      *(int4*)(&Vs[dd][kk]) = *(const int4*)(VtB + (size_t)dd * Kn + kt + kk);
    }
    __syncthreads();

    // S^T = K.Q^T: A = K-frag (rows kr0 / kr0+4), B = qf. 4 chains of 2.
    f32x4_t T0a = {0.f, 0.f, 0.f, 0.f}, T0b = {0.f, 0.f, 0.f, 0.f};
    f32x4_t T1a = {0.f, 0.f, 0.f, 0.f}, T1b = {0.f, 0.f, 0.f, 0.f};
#pragma unroll
    for (int dblk = 0; dblk < 2; dblk++) {
      f16x8_t k0f = *(const f16x8_t*)(&Ks[kr0][dblk * 32 + g * 8]);
      f16x8_t k1f = *(const f16x8_t*)(&Ks[kr0 + 4][dblk * 32 + g * 8]);
      T0a = __builtin_amdgcn_mfma_f32_16x16x32_f16(k0f, qf[dblk], T0a, 0, 0, 0);
      T1a = __builtin_amdgcn_mfma_f32_16x16x32_f16(k1f, qf[dblk], T1a, 0, 0, 0);
    }
#pragma unroll
    for (int dblk = 2; dblk < 4; dblk++) {
      f16x8_t k0f = *(const f16x8_t*)(&Ks[kr0][dblk * 32 + g * 8]);
      f16x8_t k1f = *(const f16x8_t*)(&Ks[kr0 + 4][dblk * 32 + g * 8]);
      T0b = __builtin_amdgcn_mfma_f32_16x16x32_f16(k0f, qf[dblk], T0b, 0, 0, 0);
      T1b = __builtin_amdgcn_mfma_f32_16x16x32_f16(k1f, qf[dblk], T1b, 0, 0, 0);
    }
    f32x4_t T0 = T0a + T0b, T1 = T1a + T1b;

    // p = exp(s); build PV A-fragment in-register (keys g*8+0..7 of q-row c)
    float p0[4], p1[4];
#pragma unroll
    for (int r = 0; r < 4; r++) {
      p0[r] = __expf(T0[r] * sc);
      p1[r] = __expf(T1[r] * sc);
    }
    l_lane += (p0[0] + p0[1]) + (p0[2] + p0[3]) + (p1[0] + p1[1]) + (p1[2] + p1[3]);
    f16x8_t pf;
    pf[0] = (f16)p0[0]; pf[1] = (f16)p0[1]; pf[2] = (f16)p0[2]; pf[3] = (f16)p0[3];
    pf[4] = (f16)p1[0]; pf[5] = (f16)p1[1]; pf[6] = (f16)p1[2]; pf[7] = (f16)p1[3];

    // O += P.V  (8 independent accumulator chains)
#pragma unroll
    for (int dt = 0; dt < 8; dt++) {
      f16x8_t vf = *(const f16x8_t*)(&Vs[dt * 16 + c][g * 8]);
      O[dt] = __builtin_amdgcn_mfma_f32_16x16x32_f16(pf, vf, O[dt], 0, 0, 0);
    }
  }

  // epilogue: atomic-accumulate unnormalized O and l (exact fp32 combine)
  float* oa = Oacc + ((size_t)b * Qn + q0 + wave * 16) * Dn;
#pragma unroll
  for (int r = 0; r < 4; r++) {
    const int row = g * 4 + r;
#pragma unroll
    for (int dt = 0; dt < 8; dt++)
      atomicAdd(&oa[(size_t)row * Dn + dt * 16 + c], O[dt][r]);
  }
  atomicAdd(&Lacc[(size_t)b * Qn + qrow], l_lane);
}

// ---------------- finalize: divide, masked fill ----------------
// grid (32, 16) block 256; each block does 64 q-rows.

__global__ void __launch_bounds__(256) finalize_kernel(
    const float* __restrict__ Oacc, const float* __restrict__ Lacc,
    const float* __restrict__ sv, const int* __restrict__ vlp,
    float* __restrict__ Out) {
  const int b = blockIdx.y, q0 = blockIdx.x * 64;
  const int vl = load_vl(vlp, b);
  const int tid = threadIdx.x;
  const int rsub = tid >> 5;       // 0..7
  const int d4 = (tid & 31) * 4;   // 0..124

  float4 mv = *(const float4*)(sv + b * Dn + d4);
  const float invK = 1.0f / (float)Kn;
  mv.x *= invK; mv.y *= invK; mv.z *= invK; mv.w *= invK;

#pragma unroll
  for (int pass = 0; pass < 8; pass++) {
    const int row = pass * 8 + rsub;
    const int q = q0 + row;
    float4 o;
    if (q >= vl) {
      o = mv;
    } else {
      const float li = 1.0f / Lacc[(size_t)b * Qn + q];
      float4 a = *(const float4*)(Oacc + ((size_t)b * Qn + q) * Dn + d4);
      o.x = a.x * li; o.y = a.y * li; o.z = a.z * li; o.w = a.w * li;
    }
    *(float4*)(Out + ((size_t)b * Qn + q) * Dn + d4) = o;
  }
}

// ---------------- launch ----------------

extern "C" void kernel_launch(void* const* d_in, const int* in_sizes, int n_in,
                              void* d_out, int out_size, void* d_ws, size_t ws_size,
                              hipStream_t stream) {
  const float* Qg = (const float*)d_in[0];
  const float* Kg = (const float*)d_in[1];
  const float* Vg = (const float*)d_in[2];
  const int* vl = (const int*)d_in[3];
  float* Out = (float*)d_out;

  char* ws = (char*)d_ws;
  float* Lacc = (float*)ws;                         // 131072 B
  float* sumV = (float*)(ws + 131072);              // 8192 B
  float* Oacc = (float*)(ws + 139264);              // 16777216 B
  const size_t zero_bytes = 139264 + (size_t)Bn * Qn * Dn * 4;  // 16.9 MB
  f16* Kh = (f16*)(ws + zero_bytes);                // 8 MB
  f16* Vt = (f16*)(ws + zero_bytes + (size_t)Bn * Kn * Dn * 2); // 8 MB
  f16* Qh = (f16*)(ws + zero_bytes + 2 * (size_t)Bn * Kn * Dn * 2);  // 8 MB

  hipMemsetAsync(ws, 0, zero_bytes, stream);
  prep_kernel<<<dim3(64, 4, Bn), dim3(32, 8), 0, stream>>>(Qg, Kg, Vg, Qh, Kh, Vt, sumV);
  flash_kernel<<<dim3(Qn / BQ, Bn, SEG), 256, 0, stream>>>(Qh, Kh, Vt, vl, Oacc, Lacc);
  finalize_kernel<<<dim3(Qn / BQ, Bn), 256, 0, stream>>>(Oacc, Lacc, sumV, vl, Out);
}